// Round 2
// baseline (388.594 us; speedup 1.0000x reference)
//
#include <hip/hip_runtime.h>

#define B_   4
#define N_   8192
#define D_   512
#define NH   8
#define DH   64
#define J3   1536
#define HID  512

typedef unsigned short u16;
typedef __attribute__((ext_vector_type(8))) short  bf16x8;
typedef __attribute__((ext_vector_type(8))) unsigned short u16x8;
typedef __attribute__((ext_vector_type(4))) float  f32x4;

__device__ __forceinline__ float bf2f(u16 u) {
  unsigned int i = ((unsigned int)u) << 16;
  return __builtin_bit_cast(float, i);
}
__device__ __forceinline__ u16 f2bf(float f) {
  unsigned int i = __builtin_bit_cast(unsigned int, f);
  i += 0x7fff + ((i >> 16) & 1);
  return (u16)(i >> 16);
}

#define GLOAD16(g, l) \
  __builtin_amdgcn_global_load_lds((const __attribute__((address_space(1))) void*)(g), \
                                   (__attribute__((address_space(3))) void*)(l), 16, 0, 0)

// ------------------------------------------------- transpose fp32 -> bf16
__global__ __launch_bounds__(256) void transpose_f2b(const float* __restrict__ in,
                                                     u16* __restrict__ out,
                                                     int rows, int cols) {
  int idx = blockIdx.x * 256 + threadIdx.x;
  if (idx < rows * cols) {
    int c = idx / rows, r = idx - c * rows;   // out[c*rows + r] coalesced
    out[idx] = f2bf(in[r * cols + c]);
  }
}

// ------------------------------------------------- layernorm
// x (b, d, n) fp32 -> h (b, n, d) bf16
__global__ __launch_bounds__(256) void ln_kernel(const float* __restrict__ x,
                                                 const float* __restrict__ lw,
                                                 const float* __restrict__ lb,
                                                 u16* __restrict__ h) {
  int b = blockIdx.y;
  int n = blockIdx.x * 256 + threadIdx.x;
  const float* xp = x + (long)b * D_ * N_ + n;
  float s = 0.f, s2 = 0.f;
  for (int d = 0; d < D_; d++) {
    float v = xp[(long)d * N_];
    s += v; s2 += v * v;
  }
  float mu = s * (1.0f / D_);
  float var = s2 * (1.0f / D_) - mu * mu;
  float rstd = rsqrtf(var + 1e-5f);
  u16* hp = h + ((long)b * N_ + n) * D_;
  for (int d0 = 0; d0 < D_; d0 += 8) {
    u16x8 o;
#pragma unroll
    for (int i = 0; i < 8; i++) {
      int d = d0 + i;
      float v = (xp[(long)d * N_] - mu) * rstd * lw[d] + lb[d];
      o[i] = f2bf(v);
    }
    *(u16x8*)(hp + d0) = o;
  }
}

// ------------------------------------------------- GEMM (TN), bf16 out
// C[m][n] = sum_k A[m*K+k] * B[n*K+k]; m97-style 128x128xBK32
__global__ __launch_bounds__(256) void gemm_tn_b(const u16* __restrict__ A,
                                                 const u16* __restrict__ B,
                                                 u16* __restrict__ C,
                                                 int K, int ldc) {
  __shared__ u16 As[128 * 32];
  __shared__ u16 Bs[128 * 32];
  __shared__ u16 Cs[128 * 128];
  int m0 = blockIdx.y * 128, n0 = blockIdx.x * 128;
  int tid = threadIdx.x, wave = tid >> 6, lane = tid & 63;
  int l15 = lane & 15, qd = lane >> 4;

  int ra0 = tid >> 2,          qa0 = (tid & 3) ^ ((ra0 >> 1) & 3);
  int ra1 = (tid + 256) >> 2,  qa1 = (tid & 3) ^ ((ra1 >> 1) & 3);
  const u16* gA0 = A + (long)(m0 + ra0) * K + qa0 * 8;
  const u16* gA1 = A + (long)(m0 + ra1) * K + qa1 * 8;
  const u16* gB0 = B + (long)(n0 + ra0) * K + qa0 * 8;
  const u16* gB1 = B + (long)(n0 + ra1) * K + qa1 * 8;
  u16* lA0 = As + wave * 512;
  u16* lA1 = As + 2048 + wave * 512;
  u16* lB0 = Bs + wave * 512;
  u16* lB1 = Bs + 2048 + wave * 512;

  int wm = wave & 1, wn = wave >> 1;
  int aoff[4], boff[4];
#pragma unroll
  for (int i = 0; i < 4; i++) {
    int r = wm * 64 + i * 16 + l15;
    aoff[i] = r * 32 + ((qd ^ ((r >> 1) & 3)) * 8);
    int rb = wn * 64 + i * 16 + l15;
    boff[i] = rb * 32 + ((qd ^ ((rb >> 1) & 3)) * 8);
  }

  f32x4 zero = {0.f, 0.f, 0.f, 0.f};
  f32x4 acc[4][4];
#pragma unroll
  for (int i = 0; i < 4; i++)
#pragma unroll
    for (int j = 0; j < 4; j++) acc[i][j] = zero;

  for (int k0 = 0; k0 < K; k0 += 32) {
    __syncthreads();
    GLOAD16(gA0 + k0, lA0);
    GLOAD16(gA1 + k0, lA1);
    GLOAD16(gB0 + k0, lB0);
    GLOAD16(gB1 + k0, lB1);
    __syncthreads();
    bf16x8 af[4], bf[4];
#pragma unroll
    for (int i = 0; i < 4; i++) {
      af[i] = *(const bf16x8*)(As + aoff[i]);
      bf[i] = *(const bf16x8*)(Bs + boff[i]);
    }
#pragma unroll
    for (int i = 0; i < 4; i++)
#pragma unroll
      for (int j = 0; j < 4; j++)
        acc[i][j] = __builtin_amdgcn_mfma_f32_16x16x32_bf16(af[i], bf[j], acc[i][j], 0, 0, 0);
  }
  __syncthreads();
#pragma unroll
  for (int i = 0; i < 4; i++) {
#pragma unroll
    for (int r = 0; r < 4; r++) {
      int row = wm * 64 + i * 16 + qd * 4 + r;
#pragma unroll
      for (int j = 0; j < 4; j++) {
        int col = wn * 64 + j * 16 + l15;
        Cs[row * 128 + col] = f2bf(acc[i][j][r]);
      }
    }
  }
  __syncthreads();
  for (int t = tid; t < 128 * 16; t += 256) {
    int row = t >> 4, ch = t & 15;
    *(uint4*)(C + (long)(m0 + row) * ldc + n0 + ch * 8) =
        *(const uint4*)(Cs + row * 128 + ch * 8);
  }
}

// ------------------------------------------------- GEMM (TN), fp32 out + bias
__global__ __launch_bounds__(256) void gemm_tn_f(const u16* __restrict__ A,
                                                 const u16* __restrict__ B,
                                                 float* __restrict__ C,
                                                 const float* __restrict__ bias,
                                                 int K, int ldc,
                                                 long sB, long sC) {
  __shared__ u16 As[128 * 32];
  __shared__ u16 Bs[128 * 32];
  long bz = blockIdx.z;
  B += bz * sB; C += bz * sC;
  int m0 = blockIdx.y * 128, n0 = blockIdx.x * 128;
  int tid = threadIdx.x, wave = tid >> 6, lane = tid & 63;
  int l15 = lane & 15, qd = lane >> 4;

  int ra0 = tid >> 2,          qa0 = (tid & 3) ^ ((ra0 >> 1) & 3);
  int ra1 = (tid + 256) >> 2,  qa1 = (tid & 3) ^ ((ra1 >> 1) & 3);
  const u16* gA0 = A + (long)(m0 + ra0) * K + qa0 * 8;
  const u16* gA1 = A + (long)(m0 + ra1) * K + qa1 * 8;
  const u16* gB0 = B + (long)(n0 + ra0) * K + qa0 * 8;
  const u16* gB1 = B + (long)(n0 + ra1) * K + qa1 * 8;
  u16* lA0 = As + wave * 512;
  u16* lA1 = As + 2048 + wave * 512;
  u16* lB0 = Bs + wave * 512;
  u16* lB1 = Bs + 2048 + wave * 512;

  int wm = wave & 1, wn = wave >> 1;
  int aoff[4], boff[4];
#pragma unroll
  for (int i = 0; i < 4; i++) {
    int r = wm * 64 + i * 16 + l15;
    aoff[i] = r * 32 + ((qd ^ ((r >> 1) & 3)) * 8);
    int rb = wn * 64 + i * 16 + l15;
    boff[i] = rb * 32 + ((qd ^ ((rb >> 1) & 3)) * 8);
  }

  f32x4 zero = {0.f, 0.f, 0.f, 0.f};
  f32x4 acc[4][4];
#pragma unroll
  for (int i = 0; i < 4; i++)
#pragma unroll
    for (int j = 0; j < 4; j++) acc[i][j] = zero;

  for (int k0 = 0; k0 < K; k0 += 32) {
    __syncthreads();
    GLOAD16(gA0 + k0, lA0);
    GLOAD16(gA1 + k0, lA1);
    GLOAD16(gB0 + k0, lB0);
    GLOAD16(gB1 + k0, lB1);
    __syncthreads();
    bf16x8 af[4], bf[4];
#pragma unroll
    for (int i = 0; i < 4; i++) {
      af[i] = *(const bf16x8*)(As + aoff[i]);
      bf[i] = *(const bf16x8*)(Bs + boff[i]);
    }
#pragma unroll
    for (int i = 0; i < 4; i++)
#pragma unroll
      for (int j = 0; j < 4; j++)
        acc[i][j] = __builtin_amdgcn_mfma_f32_16x16x32_bf16(af[i], bf[j], acc[i][j], 0, 0, 0);
  }
#pragma unroll
  for (int i = 0; i < 4; i++) {
#pragma unroll
    for (int r = 0; r < 4; r++) {
      int row = wm * 64 + i * 16 + qd * 4 + r;
      float bv = bias ? bias[m0 + row] : 0.0f;
#pragma unroll
      for (int j = 0; j < 4; j++) {
        int col = wn * 64 + j * 16 + l15;
        C[(long)(m0 + row) * ldc + n0 + col] = acc[i][j][r] + bv;
      }
    }
  }
}

// ------------------------------------------------- q column sums
// S[b][j] = sum_n exp(q[b,n,j]*SCALE), j in [0,512)
__global__ __launch_bounds__(256) void qsum_kernel(const u16* __restrict__ qkv,
                                                   float* __restrict__ S) {
  int b = blockIdx.z, jc = blockIdx.y, nc = blockIdx.x;
  int j = jc * 256 + threadIdx.x;
  const u16* p = qkv + ((long)b * N_ + (long)nc * 256) * J3 + j;
  float acc = 0.f;
  for (int t = 0; t < 256; t++) acc += __expf(bf2f(p[(long)t * J3]) * 0.125f);
  atomicAdd(S + b * HID + j, acc);
}

// ------------------------------------------------- context = k_sm^T @ v
__global__ __launch_bounds__(256) void ctx_kernel(const u16* __restrict__ qkv,
                                                  float* __restrict__ ctx) {
  __shared__ u16 ks[64 * 256];   // [d][token] quad-swizzled
  __shared__ u16 vs[64 * 256];   // [e][token] quad-swizzled
  int b = blockIdx.z, hh = blockIdx.y, nc = blockIdx.x;
  int tid = threadIdx.x;
  int w = tid >> 6, l = tid & 63, l15 = l & 15, qd = l >> 4;
  f32x4 zero = {0.f, 0.f, 0.f, 0.f};
  f32x4 acc[4] = {zero, zero, zero, zero};
  for (int it = 0; it < 2; it++) {
    __syncthreads();
    int tok = nc * 512 + it * 256 + tid;
    const u16* kp = qkv + ((long)b * N_ + tok) * J3 + HID + hh * DH;
    float kv[64];
#pragma unroll
    for (int i = 0; i < 8; i++) {
      u16x8 u = *(const u16x8*)(kp + i * 8);
#pragma unroll
      for (int e = 0; e < 8; e++) kv[i * 8 + e] = __expf(bf2f(u[e]));
    }
    float sum = 0.f;
#pragma unroll
    for (int d = 0; d < 64; d++) sum += kv[d];
    float inv = 1.0f / sum;
#pragma unroll
    for (int d = 0; d < 64; d++)
      ks[d * 256 + (((tid >> 3) ^ (d & 7)) * 8) + (tid & 7)] = f2bf(kv[d] * inv);
    const u16* vp = kp + HID;
#pragma unroll
    for (int i = 0; i < 8; i++) {
      u16x8 u = *(const u16x8*)(vp + i * 8);
#pragma unroll
      for (int e = 0; e < 8; e++) {
        int ee = i * 8 + e;
        vs[ee * 256 + (((tid >> 3) ^ (ee & 7)) * 8) + (tid & 7)] = u[e];
      }
    }
    __syncthreads();
#pragma unroll
    for (int kk = 0; kk < 256; kk += 32) {
      int dr = w * 16 + l15;
      int qq = (kk >> 3) + qd;
      bf16x8 af = *(const bf16x8*)(ks + dr * 256 + ((qq ^ (dr & 7)) * 8));
#pragma unroll
      for (int j = 0; j < 4; j++) {
        int er = j * 16 + l15;
        bf16x8 bfj = *(const bf16x8*)(vs + er * 256 + ((qq ^ (er & 7)) * 8));
        acc[j] = __builtin_amdgcn_mfma_f32_16x16x32_bf16(af, bfj, acc[j], 0, 0, 0);
      }
    }
  }
  float* cp = ctx + ((long)(b * NH + hh)) * DH * DH;
#pragma unroll
  for (int j = 0; j < 4; j++)
#pragma unroll
    for (int r = 0; r < 4; r++) {
      int d = w * 16 + qd * 4 + r;
      int e = j * 16 + l15;
      atomicAdd(cp + d * DH + e, acc[j][r]);
    }
}

// ------------------------------------------------- oa = q_sm @ ctx (bf16 out)
__global__ __launch_bounds__(256) void oa_kernel(const u16* __restrict__ qkv,
                                                 const float* __restrict__ S,
                                                 const float* __restrict__ ctx,
                                                 u16* __restrict__ oa) {
  __shared__ float ctxs[64 * 68];
  __shared__ float qs[32 * 68];
  __shared__ float Ss[64];
  int b = blockIdx.z, hh = blockIdx.y, t0 = blockIdx.x * 32;
  int tid = threadIdx.x;
  const float* cp = ctx + ((long)(b * NH + hh)) * DH * DH;
  for (int i = tid; i < 4096; i += 256) ctxs[(i >> 6) * 68 + (i & 63)] = cp[i];
  if (tid < 64) Ss[tid] = 1.0f / S[b * HID + hh * DH + tid];
  int tk = tid >> 3, dg = (tid & 7) * 8;
  {
    const u16* qp = qkv + ((long)b * N_ + t0 + tk) * J3 + hh * DH + dg;
    u16x8 u = *(const u16x8*)qp;
#pragma unroll
    for (int i = 0; i < 8; i++) qs[tk * 68 + dg + i] = __expf(bf2f(u[i]) * 0.125f);
  }
  __syncthreads();
  float a[8] = {0, 0, 0, 0, 0, 0, 0, 0};
  int eg = (tid & 7) * 8;
#pragma unroll 4
  for (int d = 0; d < 64; d++) {
    float qv = qs[tk * 68 + d] * Ss[d];
    const float* cr = ctxs + d * 68 + eg;
#pragma unroll
    for (int i = 0; i < 8; i++) a[i] += qv * cr[i];
  }
  u16x8 o;
#pragma unroll
  for (int i = 0; i < 8; i++) o[i] = f2bf(a[i]);
  *(u16x8*)(oa + ((long)b * N_ + t0 + tk) * HID + hh * DH + eg) = o;
}

// ------------------------------------------------- launch
extern "C" void kernel_launch(void* const* d_in, const int* in_sizes, int n_in,
                              void* d_out, int out_size, void* d_ws, size_t ws_size,
                              hipStream_t stream) {
  const float* x    = (const float*)d_in[0];
  const float* lnw  = (const float*)d_in[1];
  const float* lnb  = (const float*)d_in[2];
  const float* wqkv = (const float*)d_in[3];
  const float* wout = (const float*)d_in[4];
  const float* bout = (const float*)d_in[5];
  float* out = (float*)d_out;
  char* ws = (char*)d_ws;

  u16*  h     = (u16*)(ws + 0L);              // 33,554,432 B  (b,n,d) bf16
  u16*  qkv   = (u16*)(ws + 33554432L);       // 100,663,296 B (b,n,1536) bf16
  u16*  oa    = h;                            // aliases h (h dead after gemm1)
  u16*  wqkvT = (u16*)(ws + 134217728L);      // 1,572,864 B
  u16*  woutT = (u16*)(ws + 135790592L);      // 524,288 B
  float* S    = (float*)(ws + 136314880L);    // 8,192 B
  float* ctx  = (float*)(ws + 136323072L);    // 524,288 B

  hipMemsetAsync(S, 0, 4 * 512 * 4, stream);
  hipMemsetAsync(ctx, 0, 4 * 8 * 64 * 64 * 4, stream);

  transpose_f2b<<<dim3((512 * 1536 + 255) / 256), 256, 0, stream>>>(wqkv, wqkvT, 512, 1536);
  transpose_f2b<<<dim3((512 * 512 + 255) / 256), 256, 0, stream>>>(wout, woutT, 512, 512);

  ln_kernel<<<dim3(32, 4), 256, 0, stream>>>(x, lnw, lnb, h);

  // qkv = h @ w_qkv : M=32768, N=1536, K=512
  gemm_tn_b<<<dim3(12, 256), 256, 0, stream>>>(h, wqkvT, qkv, 512, 1536);

  qsum_kernel<<<dim3(32, 2, 4), 256, 0, stream>>>(qkv, S);
  ctx_kernel<<<dim3(16, 8, 4), 256, 0, stream>>>(qkv, ctx);
  oa_kernel<<<dim3(256, 8, 4), 256, 0, stream>>>(qkv, S, ctx, oa);

  // out[b,dO,n] = w_out^T @ oa^T + b_out : per-batch M=512, N=8192, K=512
  gemm_tn_f<<<dim3(64, 4, 4), 256, 0, stream>>>(woutT, oa, out, bout, 512, 8192,
                                                (long)8192 * 512, (long)512 * 8192);
}

// Round 4
// 318.371 us; speedup vs baseline: 1.2206x; 1.2206x over previous
//
#include <hip/hip_runtime.h>

#define B_   4
#define N_   8192
#define D_   512
#define NH   8
#define DH   64
#define HID  512

typedef unsigned short u16;
typedef __attribute__((ext_vector_type(8))) short  bf16x8;
typedef __attribute__((ext_vector_type(8))) unsigned short u16x8;
typedef __attribute__((ext_vector_type(4))) float  f32x4;

__device__ __forceinline__ float bf2f(u16 u) {
  unsigned int i = ((unsigned int)u) << 16;
  return __builtin_bit_cast(float, i);
}
__device__ __forceinline__ u16 f2bf(float f) {
  unsigned int i = __builtin_bit_cast(unsigned int, f);
  i += 0x7fff + ((i >> 16) & 1);
  return (u16)(i >> 16);
}

#define GLOAD16(g, l) \
  __builtin_amdgcn_global_load_lds((const __attribute__((address_space(1))) void*)(g), \
                                   (__attribute__((address_space(3))) void*)(l), 16, 0, 0)

// ------------------------------------------------- transpose fp32 -> bf16
__global__ __launch_bounds__(256) void transpose_f2b(const float* __restrict__ in,
                                                     u16* __restrict__ out,
                                                     int rows, int cols) {
  int idx = blockIdx.x * 256 + threadIdx.x;
  if (idx < rows * cols) {
    int c = idx / rows, r = idx - c * rows;
    out[idx] = f2bf(in[r * cols + c]);
  }
}

// ------------------------------------------------- layernorm, single HBM pass
// x (b, d, n) fp32 -> h (b, n, d) bf16.  32 tokens/block, 1024 blocks.
__global__ __launch_bounds__(256) void ln_kernel(const float* __restrict__ x,
                                                 const float* __restrict__ lw,
                                                 const float* __restrict__ lb,
                                                 u16* __restrict__ h) {
  __shared__ u16 xs[32 * 520];
  __shared__ float red[2][8][32];
  __shared__ float murs[2][32];
  __shared__ float lws[512], lbs[512];
  int b = blockIdx.y, n0 = blockIdx.x * 32;
  int t = threadIdx.x;
  lws[t] = lw[t]; lws[t + 256] = lw[t + 256];
  lbs[t] = lb[t]; lbs[t + 256] = lb[t + 256];
  int tok = t & 31, dp = t >> 5;                     // dp: 8 groups of 64 d
  const float* xp = x + (long)b * D_ * N_ + n0 + tok;
  float s = 0.f, s2 = 0.f;
#pragma unroll 8
  for (int i = 0; i < 64; i++) {
    int d = dp * 64 + i;
    float v = xp[(long)d * N_];
    s += v; s2 += v * v;
    xs[tok * 520 + d] = f2bf(v);
  }
  red[0][dp][tok] = s; red[1][dp][tok] = s2;
  __syncthreads();
  if (t < 32) {
    float S1 = 0.f, S2 = 0.f;
#pragma unroll
    for (int i = 0; i < 8; i++) { S1 += red[0][i][t]; S2 += red[1][i][t]; }
    float mu = S1 * (1.0f / 512.0f);
    float var = S2 * (1.0f / 512.0f) - mu * mu;
    murs[0][t] = mu; murs[1][t] = rsqrtf(var + 1e-5f);
  }
  __syncthreads();
  int row = t >> 3, seg = t & 7;                     // row: token, seg: 64-d group
  float mu = murs[0][row], rs = murs[1][row];
  u16* hp = h + ((long)b * N_ + n0 + row) * D_ + seg * 64;
  const u16* xr = xs + row * 520 + seg * 64;
#pragma unroll
  for (int c = 0; c < 8; c++) {
    u16x8 in8 = *(const u16x8*)(xr + c * 8);
    u16x8 o;
#pragma unroll
    for (int i = 0; i < 8; i++) {
      int d = seg * 64 + c * 8 + i;
      o[i] = f2bf((bf2f(in8[i]) - mu) * rs * lws[d] + lbs[d]);
    }
    *(u16x8*)(hp + c * 8) = o;
  }
}

// ------------------------------------------------- GEMM1: h @ wqkv with fused softmax prep
// M=32768 tokens, N=1536, K=512.  Epilogue per N-third:
//  q (n0<512):  qexp = exp(acc*0.125) token-major + colsum atomics -> S
//  k          : expkT = exp(acc) transposed (feature-major) + PER-HEAD rowsum atomics -> Z[b][h][n]
//  v          : vT = acc transposed
__global__ __launch_bounds__(256) void gemm1(const u16* __restrict__ A,
                                             const u16* __restrict__ B,
                                             u16* __restrict__ qexp,
                                             u16* __restrict__ expkT,
                                             u16* __restrict__ vT,
                                             float* __restrict__ S,
                                             float* __restrict__ Z) {
  const int K = 512;
  __shared__ u16 As[128 * 32];
  __shared__ u16 Bs[128 * 32];
  __shared__ u16 Cs[128 * 136];
  int m0 = blockIdx.y * 128, n0 = blockIdx.x * 128;
  int tid = threadIdx.x, wave = tid >> 6, lane = tid & 63;
  int l15 = lane & 15, qd = lane >> 4;

  int ra0 = tid >> 2,          qa0 = (tid & 3) ^ ((ra0 >> 1) & 3);
  int ra1 = (tid + 256) >> 2,  qa1 = (tid & 3) ^ ((ra1 >> 1) & 3);
  const u16* gA0 = A + (long)(m0 + ra0) * K + qa0 * 8;
  const u16* gA1 = A + (long)(m0 + ra1) * K + qa1 * 8;
  const u16* gB0 = B + (long)(n0 + ra0) * K + qa0 * 8;
  const u16* gB1 = B + (long)(n0 + ra1) * K + qa1 * 8;
  u16* lA0 = As + wave * 512;
  u16* lA1 = As + 2048 + wave * 512;
  u16* lB0 = Bs + wave * 512;
  u16* lB1 = Bs + 2048 + wave * 512;

  int wm = wave & 1, wn = wave >> 1;
  int aoff[4], boff[4];
#pragma unroll
  for (int i = 0; i < 4; i++) {
    int r = wm * 64 + i * 16 + l15;
    aoff[i] = r * 32 + ((qd ^ ((r >> 1) & 3)) * 8);
    int rb = wn * 64 + i * 16 + l15;
    boff[i] = rb * 32 + ((qd ^ ((rb >> 1) & 3)) * 8);
  }

  f32x4 zero = {0.f, 0.f, 0.f, 0.f};
  f32x4 acc[4][4];
#pragma unroll
  for (int i = 0; i < 4; i++)
#pragma unroll
    for (int j = 0; j < 4; j++) acc[i][j] = zero;

  for (int k0 = 0; k0 < K; k0 += 32) {
    __syncthreads();
    GLOAD16(gA0 + k0, lA0);
    GLOAD16(gA1 + k0, lA1);
    GLOAD16(gB0 + k0, lB0);
    GLOAD16(gB1 + k0, lB1);
    __syncthreads();
    bf16x8 af[4], bf[4];
#pragma unroll
    for (int i = 0; i < 4; i++) {
      af[i] = *(const bf16x8*)(As + aoff[i]);
      bf[i] = *(const bf16x8*)(Bs + boff[i]);
    }
#pragma unroll
    for (int i = 0; i < 4; i++)
#pragma unroll
      for (int j = 0; j < 4; j++)
        acc[i][j] = __builtin_amdgcn_mfma_f32_16x16x32_bf16(af[i], bf[j], acc[i][j], 0, 0, 0);
  }

  int third = n0 >> 9;
  int n0t = n0 & 511;
  int b = m0 >> 13;
  int tloc = m0 & 8191;

  if (third == 0) {
#pragma unroll
    for (int i = 0; i < 4; i++)
#pragma unroll
      for (int j = 0; j < 4; j++)
#pragma unroll
        for (int r = 0; r < 4; r++) acc[i][j][r] = __expf(acc[i][j][r] * 0.125f);
#pragma unroll
    for (int j = 0; j < 4; j++) {
      float ps = 0.f;
#pragma unroll
      for (int i = 0; i < 4; i++)
#pragma unroll
        for (int r = 0; r < 4; r++) ps += acc[i][j][r];
      ps += __shfl_xor(ps, 16);
      ps += __shfl_xor(ps, 32);
      if (qd == 0) atomicAdd(S + b * 512 + n0t + wn * 64 + j * 16 + l15, ps);
    }
  } else if (third == 1) {
#pragma unroll
    for (int i = 0; i < 4; i++)
#pragma unroll
      for (int j = 0; j < 4; j++)
#pragma unroll
        for (int r = 0; r < 4; r++) acc[i][j][r] = __expf(acc[i][j][r]);
    // per-head partition function: this wave's 64 cols (wn half) == one head
    int head = (n0t >> 6) + wn;
#pragma unroll
    for (int i = 0; i < 4; i++)
#pragma unroll
      for (int r = 0; r < 4; r++) {
        float rs = acc[i][0][r] + acc[i][1][r] + acc[i][2][r] + acc[i][3][r];
        rs += __shfl_xor(rs, 1);
        rs += __shfl_xor(rs, 2);
        rs += __shfl_xor(rs, 4);
        rs += __shfl_xor(rs, 8);
        if (l15 == 0)
          atomicAdd(Z + ((long)b * NH + head) * 8192 + tloc + wm * 64 + i * 16 + qd * 4 + r, rs);
      }
  }

  // stage into Cs: q row-major [token][col]; k/v transposed [col][token]
  if (third == 0) {
#pragma unroll
    for (int i = 0; i < 4; i++)
#pragma unroll
      for (int r = 0; r < 4; r++)
#pragma unroll
        for (int j = 0; j < 4; j++)
          Cs[(wm * 64 + i * 16 + qd * 4 + r) * 136 + wn * 64 + j * 16 + l15] =
              f2bf(acc[i][j][r]);
  } else {
#pragma unroll
    for (int i = 0; i < 4; i++)
#pragma unroll
      for (int r = 0; r < 4; r++)
#pragma unroll
        for (int j = 0; j < 4; j++)
          Cs[(wn * 64 + j * 16 + l15) * 136 + wm * 64 + i * 16 + qd * 4 + r] =
              f2bf(acc[i][j][r]);
  }
  __syncthreads();

  u16* dst; long ldg;
  if (third == 0)      { dst = qexp  + ((long)b * N_ + tloc) * 512 + n0t;  ldg = 512; }
  else if (third == 1) { dst = expkT + ((long)b * 512 + n0t) * 8192 + tloc; ldg = 8192; }
  else                 { dst = vT    + ((long)b * 512 + n0t) * 8192 + tloc; ldg = 8192; }

#pragma unroll
  for (int outer = 0; outer < 2; outer++) {
    int row = outer * 64 + wave * 16 + (lane >> 2);
    int seg = lane & 3;
    const u16* src = Cs + row * 136;
    u16* dp = dst + (long)row * ldg;
#pragma unroll
    for (int p = 0; p < 4; p++)
      *(uint4*)(dp + p * 32 + seg * 8) = *(const uint4*)(src + p * 32 + seg * 8);
  }
}

// ------------------------------------------------- Z -> 1/Z  (4*8*8192 elements)
__global__ __launch_bounds__(256) void zrecip(float* __restrict__ Z) {
  int i = blockIdx.x * 256 + threadIdx.x;
  Z[i] = 1.0f / Z[i];
}

// ------------------------------------------------- ctx[b,h,d,e] += sum_n expkT[d,n] * vT[e,n] * Zr[b,h,n]
// grid (16 kchunks, 8 h, 4 b); 512 tokens/block in 4 stages of 128
__global__ __launch_bounds__(256) void ctx_kernel(const u16* __restrict__ expkT,
                                                  const u16* __restrict__ vT,
                                                  const float* __restrict__ Zr,
                                                  float* __restrict__ ctx) {
  __shared__ u16 As[64 * 128];
  __shared__ u16 Bs[64 * 128];
  int kc = blockIdx.x, hh = blockIdx.y, b = blockIdx.z;
  int t = threadIdx.x, w = t >> 6, l = t & 63, l15 = l & 15, qd = l >> 4;
  long nbase = (long)kc * 512;
  const u16* Abase = expkT + ((long)b * 512 + hh * 64) * 8192 + nbase;
  const u16* Bbase = vT   + ((long)b * 512 + hh * 64) * 8192 + nbase;
  const float* Zb = Zr + ((long)b * NH + hh) * 8192 + nbase;

  f32x4 zero = {0.f, 0.f, 0.f, 0.f};
  f32x4 acc[4] = {zero, zero, zero, zero};

  int brow = t >> 2;                    // B staging: row (e), 4 chunks/thread
  for (int s = 0; s < 4; s++) {
    long ko = (long)s * 128;
    __syncthreads();
    // A: global_load_lds, swizzled (slot g holds global chunk g^(row&15))
#pragma unroll
    for (int si = 0; si < 4; si++) {
      int qq = si * 4 + w;              // 0..15, wave-uniform
      int row = qq * 4 + (l >> 4);
      int gs = (l & 15) ^ (row & 15);
      GLOAD16(Abase + (long)row * 8192 + ko + gs * 8, As + qq * 512);
    }
    // B: VALU staging with 1/Z scaling, same swizzle
    {
      const u16* src = Bbase + (long)brow * 8192 + ko;
#pragma unroll
      for (int cc = 0; cc < 4; cc++) {
        int c = (t & 3) * 4 + cc;
        u16x8 v8 = *(const u16x8*)(src + c * 8);
        float4 z0 = *(const float4*)(Zb + ko + c * 8);
        float4 z1 = *(const float4*)(Zb + ko + c * 8 + 4);
        u16x8 o;
        o[0] = f2bf(bf2f(v8[0]) * z0.x); o[1] = f2bf(bf2f(v8[1]) * z0.y);
        o[2] = f2bf(bf2f(v8[2]) * z0.z); o[3] = f2bf(bf2f(v8[3]) * z0.w);
        o[4] = f2bf(bf2f(v8[4]) * z1.x); o[5] = f2bf(bf2f(v8[5]) * z1.y);
        o[6] = f2bf(bf2f(v8[6]) * z1.z); o[7] = f2bf(bf2f(v8[7]) * z1.w);
        *(u16x8*)(Bs + brow * 128 + ((c ^ (brow & 15)) * 8)) = o;
      }
    }
    __syncthreads();
#pragma unroll
    for (int kk = 0; kk < 4; kk++) {
      int ar = w * 16 + l15;
      bf16x8 af = *(const bf16x8*)(As + ar * 128 + (((kk * 4 + qd) ^ (ar & 15)) * 8));
#pragma unroll
      for (int j = 0; j < 4; j++) {
        int br = j * 16 + l15;
        bf16x8 bf8 = *(const bf16x8*)(Bs + br * 128 + (((kk * 4 + qd) ^ (br & 15)) * 8));
        acc[j] = __builtin_amdgcn_mfma_f32_16x16x32_bf16(af, bf8, acc[j], 0, 0, 0);
      }
    }
  }
  float* cp = ctx + ((long)(b * NH + hh)) * DH * DH;
#pragma unroll
  for (int j = 0; j < 4; j++)
#pragma unroll
    for (int r = 0; r < 4; r++)
      atomicAdd(cp + (w * 16 + qd * 4 + r) * 64 + j * 16 + l15, acc[j][r]);
}

// ------------------------------------------------- Mt[b][do][hd] = (sum_e ctx[b,h,d,e]*wout[h*64+e][do]) / S[b][hd]
// grid (8 dotile, 8 h, 4 b)
__global__ __launch_bounds__(256) void mprime(const float* __restrict__ ctx,
                                              const float* __restrict__ wout,
                                              const float* __restrict__ S,
                                              u16* __restrict__ Mt) {
  __shared__ float ws[64 * 65];
  __shared__ float cs[64 * 65];
  int dt = blockIdx.x, hh = blockIdx.y, b = blockIdx.z;
  int t = threadIdx.x;
  {
    int e = t >> 2;
#pragma unroll
    for (int ii = 0; ii < 4; ii++) {
      int col = (t & 3) * 16 + ii * 4;
      float4 v = *(const float4*)(wout + (long)(hh * 64 + e) * 512 + dt * 64 + col);
      ws[e * 65 + col] = v.x; ws[e * 65 + col + 1] = v.y;
      ws[e * 65 + col + 2] = v.z; ws[e * 65 + col + 3] = v.w;
      float4 c = *(const float4*)(ctx + ((long)(b * NH + hh)) * 4096 + (long)e * 64 + col);
      cs[e * 65 + col] = c.x; cs[e * 65 + col + 1] = c.y;
      cs[e * 65 + col + 2] = c.z; cs[e * 65 + col + 3] = c.w;
    }
  }
  __syncthreads();
  int dol = t & 63, dg = t >> 6;
#pragma unroll
  for (int dd = 0; dd < 16; dd++) {
    int d = dg * 16 + dd;
    float v = 0.f;
#pragma unroll 8
    for (int e = 0; e < 64; e++) v += cs[d * 65 + e] * ws[e * 65 + dol];
    float sv = S[b * 512 + hh * 64 + d];
    Mt[(long)b * 262144 + (long)(dt * 64 + dol) * 512 + hh * 64 + d] = f2bf(v / sv);
  }
}

// ------------------------------------------------- GEMM2 (TN), fp32 out + bias
// out[b][do][n] = sum_hd Mt[b][do][hd] * qexp[b][n][hd] + bout[do]
__global__ __launch_bounds__(256) void gemm_tn_f(const u16* __restrict__ A,
                                                 const u16* __restrict__ B,
                                                 float* __restrict__ C,
                                                 const float* __restrict__ bias,
                                                 int K, int ldc,
                                                 long sA, long sB, long sC) {
  __shared__ u16 As[128 * 32];
  __shared__ u16 Bs[128 * 32];
  long bz = blockIdx.z;
  A += bz * sA; B += bz * sB; C += bz * sC;
  int m0 = blockIdx.y * 128, n0 = blockIdx.x * 128;
  int tid = threadIdx.x, wave = tid >> 6, lane = tid & 63;
  int l15 = lane & 15, qd = lane >> 4;

  int ra0 = tid >> 2,          qa0 = (tid & 3) ^ ((ra0 >> 1) & 3);
  int ra1 = (tid + 256) >> 2,  qa1 = (tid & 3) ^ ((ra1 >> 1) & 3);
  const u16* gA0 = A + (long)(m0 + ra0) * K + qa0 * 8;
  const u16* gA1 = A + (long)(m0 + ra1) * K + qa1 * 8;
  const u16* gB0 = B + (long)(n0 + ra0) * K + qa0 * 8;
  const u16* gB1 = B + (long)(n0 + ra1) * K + qa1 * 8;
  u16* lA0 = As + wave * 512;
  u16* lA1 = As + 2048 + wave * 512;
  u16* lB0 = Bs + wave * 512;
  u16* lB1 = Bs + 2048 + wave * 512;

  int wm = wave & 1, wn = wave >> 1;
  int aoff[4], boff[4];
#pragma unroll
  for (int i = 0; i < 4; i++) {
    int r = wm * 64 + i * 16 + l15;
    aoff[i] = r * 32 + ((qd ^ ((r >> 1) & 3)) * 8);
    int rb = wn * 64 + i * 16 + l15;
    boff[i] = rb * 32 + ((qd ^ ((rb >> 1) & 3)) * 8);
  }

  f32x4 zero = {0.f, 0.f, 0.f, 0.f};
  f32x4 acc[4][4];
#pragma unroll
  for (int i = 0; i < 4; i++)
#pragma unroll
    for (int j = 0; j < 4; j++) acc[i][j] = zero;

  for (int k0 = 0; k0 < K; k0 += 32) {
    __syncthreads();
    GLOAD16(gA0 + k0, lA0);
    GLOAD16(gA1 + k0, lA1);
    GLOAD16(gB0 + k0, lB0);
    GLOAD16(gB1 + k0, lB1);
    __syncthreads();
    bf16x8 af[4], bf[4];
#pragma unroll
    for (int i = 0; i < 4; i++) {
      af[i] = *(const bf16x8*)(As + aoff[i]);
      bf[i] = *(const bf16x8*)(Bs + boff[i]);
    }
#pragma unroll
    for (int i = 0; i < 4; i++)
#pragma unroll
      for (int j = 0; j < 4; j++)
        acc[i][j] = __builtin_amdgcn_mfma_f32_16x16x32_bf16(af[i], bf[j], acc[i][j], 0, 0, 0);
  }
#pragma unroll
  for (int i = 0; i < 4; i++) {
#pragma unroll
    for (int r = 0; r < 4; r++) {
      int row = wm * 64 + i * 16 + qd * 4 + r;
      float bv = bias ? bias[m0 + row] : 0.0f;
#pragma unroll
      for (int j = 0; j < 4; j++) {
        int col = wn * 64 + j * 16 + l15;
        C[(long)(m0 + row) * ldc + n0 + col] = acc[i][j][r] + bv;
      }
    }
  }
}

// ------------------------------------------------- launch
extern "C" void kernel_launch(void* const* d_in, const int* in_sizes, int n_in,
                              void* d_out, int out_size, void* d_ws, size_t ws_size,
                              hipStream_t stream) {
  const float* x    = (const float*)d_in[0];
  const float* lnw  = (const float*)d_in[1];
  const float* lnb  = (const float*)d_in[2];
  const float* wqkv = (const float*)d_in[3];
  const float* wout = (const float*)d_in[4];
  const float* bout = (const float*)d_in[5];
  float* out = (float*)d_out;
  char* ws = (char*)d_ws;

  u16*  h     = (u16*)(ws + 0L);              // 32 MB (b,n,d) bf16
  u16*  qexp  = (u16*)(ws + 33554432L);       // 32 MB (b,n,512) bf16
  u16*  expkT = (u16*)(ws + 67108864L);       // 32 MB (b,512,n) bf16
  u16*  vT    = (u16*)(ws + 100663296L);      // 32 MB (b,512,n) bf16
  u16*  wqkvT = (u16*)(ws + 134217728L);      // 1.5 MB
  u16*  Mt    = (u16*)(ws + 134217728L);      // 2 MB, reuses wqkvT region (after gemm1)
  float* S    = (float*)(ws + 136314880L);    // 8 KB
  float* ctx  = (float*)(ws + 0L);            // 512 KB, aliases h (dead after gemm1)
  // Z[b][h][n] (1 MB) lives in the FRONT of d_out: dead before gemm_tn_f writes out.
  float* Z    = (float*)d_out;

  hipMemsetAsync(S, 0, 4 * 512 * 4, stream);
  hipMemsetAsync(Z, 0, (long)B_ * NH * 8192 * 4, stream);

  transpose_f2b<<<dim3((512 * 1536 + 255) / 256), 256, 0, stream>>>(wqkv, wqkvT, 512, 1536);

  ln_kernel<<<dim3(256, 4), 256, 0, stream>>>(x, lnw, lnb, h);

  gemm1<<<dim3(12, 256), 256, 0, stream>>>(h, wqkvT, qexp, expkT, vT, S, Z);

  zrecip<<<dim3(1024), 256, 0, stream>>>(Z);

  hipMemsetAsync(ctx, 0, 4 * 8 * 64 * 64 * 4, stream);  // after gemm1 (aliases h)

  ctx_kernel<<<dim3(16, 8, 4), 256, 0, stream>>>(expkT, vT, Z, ctx);

  mprime<<<dim3(8, 8, 4), 256, 0, stream>>>(ctx, wout, S, Mt);

  gemm_tn_f<<<dim3(64, 4, 4), 256, 0, stream>>>(Mt, qexp, out, bout, 512, 8192,
                                                262144L, (long)8192 * 512, (long)512 * 8192);
}

// Round 5
// 312.711 us; speedup vs baseline: 1.2427x; 1.0181x over previous
//
#include <hip/hip_runtime.h>

#define B_   4
#define N_   8192
#define D_   512
#define NH   8
#define DH   64
#define HID  512

typedef unsigned short u16;
typedef __attribute__((ext_vector_type(8))) short  bf16x8;
typedef __attribute__((ext_vector_type(8))) unsigned short u16x8;
typedef __attribute__((ext_vector_type(4))) float  f32x4;

__device__ __forceinline__ float bf2f(u16 u) {
  unsigned int i = ((unsigned int)u) << 16;
  return __builtin_bit_cast(float, i);
}
__device__ __forceinline__ u16 f2bf(float f) {
  unsigned int i = __builtin_bit_cast(unsigned int, f);
  i += 0x7fff + ((i >> 16) & 1);
  return (u16)(i >> 16);
}

#define GLOAD16(g, l) \
  __builtin_amdgcn_global_load_lds((const __attribute__((address_space(1))) void*)(g), \
                                   (__attribute__((address_space(3))) void*)(l), 16, 0, 0)

// ------------------------------------------------- tiled transpose fp32 -> bf16
// out[c][r] = in[r][c]; grid (cols/64, rows/64)
__global__ __launch_bounds__(256) void transpose_f2b(const float* __restrict__ in,
                                                     u16* __restrict__ out,
                                                     int rows, int cols) {
  __shared__ u16 tile[64][65];
  int c0 = blockIdx.x * 64, r0 = blockIdx.y * 64;
  int t = threadIdx.x;
  int rl = t >> 6, cl = t & 63;
#pragma unroll
  for (int i = 0; i < 16; i++) {
    int r = i * 4 + rl;
    tile[r][cl] = f2bf(in[(long)(r0 + r) * cols + c0 + cl]);
  }
  __syncthreads();
  int c4 = t >> 6, rr = t & 63;
#pragma unroll
  for (int i = 0; i < 16; i++) {
    int c = i * 4 + c4;
    out[(long)(c0 + c) * rows + r0 + rr] = tile[rr][c];
  }
}

// ------------------------------------------------- layernorm, single HBM pass
// x (b, d, n) fp32 -> h (b, n, d) bf16.  32 tokens/block, 1024 blocks.
__global__ __launch_bounds__(256) void ln_kernel(const float* __restrict__ x,
                                                 const float* __restrict__ lw,
                                                 const float* __restrict__ lb,
                                                 u16* __restrict__ h) {
  __shared__ u16 xs[32 * 520];
  __shared__ float red[2][8][32];
  __shared__ float murs[2][32];
  __shared__ float lws[512], lbs[512];
  int b = blockIdx.y, n0 = blockIdx.x * 32;
  int t = threadIdx.x;
  lws[t] = lw[t]; lws[t + 256] = lw[t + 256];
  lbs[t] = lb[t]; lbs[t + 256] = lb[t + 256];
  int tok = t & 31, dp = t >> 5;                     // dp: 8 groups of 64 d
  const float* xp = x + (long)b * D_ * N_ + n0 + tok;
  float s = 0.f, s2 = 0.f;
#pragma unroll 8
  for (int i = 0; i < 64; i++) {
    int d = dp * 64 + i;
    float v = xp[(long)d * N_];
    s += v; s2 += v * v;
    xs[tok * 520 + d] = f2bf(v);
  }
  red[0][dp][tok] = s; red[1][dp][tok] = s2;
  __syncthreads();
  if (t < 32) {
    float S1 = 0.f, S2 = 0.f;
#pragma unroll
    for (int i = 0; i < 8; i++) { S1 += red[0][i][t]; S2 += red[1][i][t]; }
    float mu = S1 * (1.0f / 512.0f);
    float var = S2 * (1.0f / 512.0f) - mu * mu;
    murs[0][t] = mu; murs[1][t] = rsqrtf(var + 1e-5f);
  }
  __syncthreads();
  // full-line stores: 8 consecutive lanes cover 128B of one token row
  int row = t >> 3, seg = t & 7;
  float mu = murs[0][row], rs = murs[1][row];
  u16* hp = h + ((long)b * N_ + n0 + row) * D_;
  const u16* xr = xs + row * 520;
#pragma unroll
  for (int c = 0; c < 8; c++) {
    int d0 = c * 64 + seg * 8;
    u16x8 in8 = *(const u16x8*)(xr + d0);
    u16x8 o;
#pragma unroll
    for (int i = 0; i < 8; i++) {
      int d = d0 + i;
      o[i] = f2bf((bf2f(in8[i]) - mu) * rs * lws[d] + lbs[d]);
    }
    *(u16x8*)(hp + d0) = o;
  }
}

// ------------------------------------------------- GEMM1: h @ wqkv with fused softmax prep
__global__ __launch_bounds__(256) void gemm1(const u16* __restrict__ A,
                                             const u16* __restrict__ B,
                                             u16* __restrict__ qexp,
                                             u16* __restrict__ expkT,
                                             u16* __restrict__ vT,
                                             float* __restrict__ S,
                                             float* __restrict__ Z) {
  const int K = 512;
  __shared__ u16 As[128 * 32];
  __shared__ u16 Bs[128 * 32];
  __shared__ u16 Cs[128 * 136];
  int m0 = blockIdx.y * 128, n0 = blockIdx.x * 128;
  int tid = threadIdx.x, wave = tid >> 6, lane = tid & 63;
  int l15 = lane & 15, qd = lane >> 4;

  int ra0 = tid >> 2,          qa0 = (tid & 3) ^ ((ra0 >> 1) & 3);
  int ra1 = (tid + 256) >> 2,  qa1 = (tid & 3) ^ ((ra1 >> 1) & 3);
  const u16* gA0 = A + (long)(m0 + ra0) * K + qa0 * 8;
  const u16* gA1 = A + (long)(m0 + ra1) * K + qa1 * 8;
  const u16* gB0 = B + (long)(n0 + ra0) * K + qa0 * 8;
  const u16* gB1 = B + (long)(n0 + ra1) * K + qa1 * 8;
  u16* lA0 = As + wave * 512;
  u16* lA1 = As + 2048 + wave * 512;
  u16* lB0 = Bs + wave * 512;
  u16* lB1 = Bs + 2048 + wave * 512;

  int wm = wave & 1, wn = wave >> 1;
  int aoff[4], boff[4];
#pragma unroll
  for (int i = 0; i < 4; i++) {
    int r = wm * 64 + i * 16 + l15;
    aoff[i] = r * 32 + ((qd ^ ((r >> 1) & 3)) * 8);
    int rb = wn * 64 + i * 16 + l15;
    boff[i] = rb * 32 + ((qd ^ ((rb >> 1) & 3)) * 8);
  }

  f32x4 zero = {0.f, 0.f, 0.f, 0.f};
  f32x4 acc[4][4];
#pragma unroll
  for (int i = 0; i < 4; i++)
#pragma unroll
    for (int j = 0; j < 4; j++) acc[i][j] = zero;

  for (int k0 = 0; k0 < K; k0 += 32) {
    __syncthreads();
    GLOAD16(gA0 + k0, lA0);
    GLOAD16(gA1 + k0, lA1);
    GLOAD16(gB0 + k0, lB0);
    GLOAD16(gB1 + k0, lB1);
    __syncthreads();
    bf16x8 af[4], bf[4];
#pragma unroll
    for (int i = 0; i < 4; i++) {
      af[i] = *(const bf16x8*)(As + aoff[i]);
      bf[i] = *(const bf16x8*)(Bs + boff[i]);
    }
#pragma unroll
    for (int i = 0; i < 4; i++)
#pragma unroll
      for (int j = 0; j < 4; j++)
        acc[i][j] = __builtin_amdgcn_mfma_f32_16x16x32_bf16(af[i], bf[j], acc[i][j], 0, 0, 0);
  }

  int third = n0 >> 9;
  int n0t = n0 & 511;
  int b = m0 >> 13;
  int tloc = m0 & 8191;

  if (third == 0) {
#pragma unroll
    for (int i = 0; i < 4; i++)
#pragma unroll
      for (int j = 0; j < 4; j++)
#pragma unroll
        for (int r = 0; r < 4; r++) acc[i][j][r] = __expf(acc[i][j][r] * 0.125f);
#pragma unroll
    for (int j = 0; j < 4; j++) {
      float ps = 0.f;
#pragma unroll
      for (int i = 0; i < 4; i++)
#pragma unroll
        for (int r = 0; r < 4; r++) ps += acc[i][j][r];
      ps += __shfl_xor(ps, 16);
      ps += __shfl_xor(ps, 32);
      if (qd == 0) atomicAdd(S + b * 512 + n0t + wn * 64 + j * 16 + l15, ps);
    }
  } else if (third == 1) {
#pragma unroll
    for (int i = 0; i < 4; i++)
#pragma unroll
      for (int j = 0; j < 4; j++)
#pragma unroll
        for (int r = 0; r < 4; r++) acc[i][j][r] = __expf(acc[i][j][r]);
    int head = (n0t >> 6) + wn;
#pragma unroll
    for (int i = 0; i < 4; i++)
#pragma unroll
      for (int r = 0; r < 4; r++) {
        float rs = acc[i][0][r] + acc[i][1][r] + acc[i][2][r] + acc[i][3][r];
        rs += __shfl_xor(rs, 1);
        rs += __shfl_xor(rs, 2);
        rs += __shfl_xor(rs, 4);
        rs += __shfl_xor(rs, 8);
        if (l15 == 0)
          atomicAdd(Z + ((long)b * NH + head) * 8192 + tloc + wm * 64 + i * 16 + qd * 4 + r, rs);
      }
  }

  if (third == 0) {
#pragma unroll
    for (int i = 0; i < 4; i++)
#pragma unroll
      for (int r = 0; r < 4; r++)
#pragma unroll
        for (int j = 0; j < 4; j++)
          Cs[(wm * 64 + i * 16 + qd * 4 + r) * 136 + wn * 64 + j * 16 + l15] =
              f2bf(acc[i][j][r]);
  } else {
#pragma unroll
    for (int i = 0; i < 4; i++)
#pragma unroll
      for (int r = 0; r < 4; r++)
#pragma unroll
        for (int j = 0; j < 4; j++)
          Cs[(wn * 64 + j * 16 + l15) * 136 + wm * 64 + i * 16 + qd * 4 + r] =
              f2bf(acc[i][j][r]);
  }
  __syncthreads();

  u16* dst; long ldg;
  if (third == 0)      { dst = qexp  + ((long)b * N_ + tloc) * 512 + n0t;  ldg = 512; }
  else if (third == 1) { dst = expkT + ((long)b * 512 + n0t) * 8192 + tloc; ldg = 8192; }
  else                 { dst = vT    + ((long)b * 512 + n0t) * 8192 + tloc; ldg = 8192; }

  // full-line stores: 8 lanes cover 128B contiguous of one row per instruction
  int seg = lane & 7;
#pragma unroll
  for (int outer = 0; outer < 2; outer++)
#pragma unroll
    for (int rr = 0; rr < 2; rr++) {
      int row = outer * 64 + wave * 16 + rr * 8 + (lane >> 3);
      const u16* src = Cs + row * 136;
      u16* dp = dst + (long)row * ldg;
#pragma unroll
      for (int p = 0; p < 2; p++)
        *(uint4*)(dp + p * 64 + seg * 8) = *(const uint4*)(src + p * 64 + seg * 8);
    }
}

// ------------------------------------------------- Z -> 1/Z  (4*8*8192 elements)
__global__ __launch_bounds__(256) void zrecip(float* __restrict__ Z) {
  int i = blockIdx.x * 256 + threadIdx.x;
  Z[i] = 1.0f / Z[i];
}

// ------------------------------------------------- ctx[b,h,d,e] += sum_n expkT[d,n] * vT[e,n] * Zr[b,h,n]
__global__ __launch_bounds__(256) void ctx_kernel(const u16* __restrict__ expkT,
                                                  const u16* __restrict__ vT,
                                                  const float* __restrict__ Zr,
                                                  float* __restrict__ ctx) {
  __shared__ u16 As[64 * 128];
  __shared__ u16 Bs[64 * 128];
  int kc = blockIdx.x, hh = blockIdx.y, b = blockIdx.z;
  int t = threadIdx.x, w = t >> 6, l = t & 63, l15 = l & 15, qd = l >> 4;
  long nbase = (long)kc * 512;
  const u16* Abase = expkT + ((long)b * 512 + hh * 64) * 8192 + nbase;
  const u16* Bbase = vT   + ((long)b * 512 + hh * 64) * 8192 + nbase;
  const float* Zb = Zr + ((long)b * NH + hh) * 8192 + nbase;

  f32x4 zero = {0.f, 0.f, 0.f, 0.f};
  f32x4 acc[4] = {zero, zero, zero, zero};

  int brow = t >> 2;
  for (int s = 0; s < 4; s++) {
    long ko = (long)s * 128;
    __syncthreads();
#pragma unroll
    for (int si = 0; si < 4; si++) {
      int qq = si * 4 + w;
      int row = qq * 4 + (l >> 4);
      int gs = (l & 15) ^ (row & 15);
      GLOAD16(Abase + (long)row * 8192 + ko + gs * 8, As + qq * 512);
    }
    {
      const u16* src = Bbase + (long)brow * 8192 + ko;
#pragma unroll
      for (int cc = 0; cc < 4; cc++) {
        int c = (t & 3) * 4 + cc;
        u16x8 v8 = *(const u16x8*)(src + c * 8);
        float4 z0 = *(const float4*)(Zb + ko + c * 8);
        float4 z1 = *(const float4*)(Zb + ko + c * 8 + 4);
        u16x8 o;
        o[0] = f2bf(bf2f(v8[0]) * z0.x); o[1] = f2bf(bf2f(v8[1]) * z0.y);
        o[2] = f2bf(bf2f(v8[2]) * z0.z); o[3] = f2bf(bf2f(v8[3]) * z0.w);
        o[4] = f2bf(bf2f(v8[4]) * z1.x); o[5] = f2bf(bf2f(v8[5]) * z1.y);
        o[6] = f2bf(bf2f(v8[6]) * z1.z); o[7] = f2bf(bf2f(v8[7]) * z1.w);
        *(u16x8*)(Bs + brow * 128 + ((c ^ (brow & 15)) * 8)) = o;
      }
    }
    __syncthreads();
#pragma unroll
    for (int kk = 0; kk < 4; kk++) {
      int ar = w * 16 + l15;
      bf16x8 af = *(const bf16x8*)(As + ar * 128 + (((kk * 4 + qd) ^ (ar & 15)) * 8));
#pragma unroll
      for (int j = 0; j < 4; j++) {
        int br = j * 16 + l15;
        bf16x8 bf8 = *(const bf16x8*)(Bs + br * 128 + (((kk * 4 + qd) ^ (br & 15)) * 8));
        acc[j] = __builtin_amdgcn_mfma_f32_16x16x32_bf16(af, bf8, acc[j], 0, 0, 0);
      }
    }
  }
  float* cp = ctx + ((long)(b * NH + hh)) * DH * DH;
#pragma unroll
  for (int j = 0; j < 4; j++)
#pragma unroll
    for (int r = 0; r < 4; r++)
      atomicAdd(cp + (w * 16 + qd * 4 + r) * 64 + j * 16 + l15, acc[j][r]);
}

// ------------------------------------------------- Mt[b][do][hd] = (sum_e ctx[b,h,d,e]*wout[h*64+e][do]) / S[b][hd]
__global__ __launch_bounds__(256) void mprime(const float* __restrict__ ctx,
                                              const float* __restrict__ wout,
                                              const float* __restrict__ S,
                                              u16* __restrict__ Mt) {
  __shared__ float ws[64 * 65];
  __shared__ float cs[64 * 65];
  int dt = blockIdx.x, hh = blockIdx.y, b = blockIdx.z;
  int t = threadIdx.x;
  {
    int e = t >> 2;
#pragma unroll
    for (int ii = 0; ii < 4; ii++) {
      int col = (t & 3) * 16 + ii * 4;
      float4 v = *(const float4*)(wout + (long)(hh * 64 + e) * 512 + dt * 64 + col);
      ws[e * 65 + col] = v.x; ws[e * 65 + col + 1] = v.y;
      ws[e * 65 + col + 2] = v.z; ws[e * 65 + col + 3] = v.w;
      float4 c = *(const float4*)(ctx + ((long)(b * NH + hh)) * 4096 + (long)e * 64 + col);
      cs[e * 65 + col] = c.x; cs[e * 65 + col + 1] = c.y;
      cs[e * 65 + col + 2] = c.z; cs[e * 65 + col + 3] = c.w;
    }
  }
  __syncthreads();
  int dol = t & 63, dg = t >> 6;
#pragma unroll
  for (int dd = 0; dd < 16; dd++) {
    int d = dg * 16 + dd;
    float v = 0.f;
#pragma unroll 8
    for (int e = 0; e < 64; e++) v += cs[d * 65 + e] * ws[e * 65 + dol];
    float sv = S[b * 512 + hh * 64 + d];
    Mt[(long)b * 262144 + (long)(dt * 64 + dol) * 512 + hh * 64 + d] = f2bf(v / sv);
  }
}

// ------------------------------------------------- GEMM2 (TN), fp32 out + bias, LDS-restaged stores
// grid (4 M, 64 N, 4 b)
__global__ __launch_bounds__(256) void gemm_tn_f(const u16* __restrict__ A,
                                                 const u16* __restrict__ B,
                                                 float* __restrict__ C,
                                                 const float* __restrict__ bias,
                                                 int K, int ldc,
                                                 long sA, long sB, long sC) {
  __shared__ u16 As[128 * 32];
  __shared__ u16 Bs[128 * 32];
  __shared__ float Cf[64 * 133];
  long bz = blockIdx.z;
  A += bz * sA; B += bz * sB; C += bz * sC;
  int m0 = blockIdx.x * 128, n0 = blockIdx.y * 128;
  int tid = threadIdx.x, wave = tid >> 6, lane = tid & 63;
  int l15 = lane & 15, qd = lane >> 4;

  int ra0 = tid >> 2,          qa0 = (tid & 3) ^ ((ra0 >> 1) & 3);
  int ra1 = (tid + 256) >> 2,  qa1 = (tid & 3) ^ ((ra1 >> 1) & 3);
  const u16* gA0 = A + (long)(m0 + ra0) * K + qa0 * 8;
  const u16* gA1 = A + (long)(m0 + ra1) * K + qa1 * 8;
  const u16* gB0 = B + (long)(n0 + ra0) * K + qa0 * 8;
  const u16* gB1 = B + (long)(n0 + ra1) * K + qa1 * 8;
  u16* lA0 = As + wave * 512;
  u16* lA1 = As + 2048 + wave * 512;
  u16* lB0 = Bs + wave * 512;
  u16* lB1 = Bs + 2048 + wave * 512;

  int wm = wave & 1, wn = wave >> 1;
  int aoff[4], boff[4];
#pragma unroll
  for (int i = 0; i < 4; i++) {
    int r = wm * 64 + i * 16 + l15;
    aoff[i] = r * 32 + ((qd ^ ((r >> 1) & 3)) * 8);
    int rb = wn * 64 + i * 16 + l15;
    boff[i] = rb * 32 + ((qd ^ ((rb >> 1) & 3)) * 8);
  }

  f32x4 zero = {0.f, 0.f, 0.f, 0.f};
  f32x4 acc[4][4];
#pragma unroll
  for (int i = 0; i < 4; i++)
#pragma unroll
    for (int j = 0; j < 4; j++) acc[i][j] = zero;

  for (int k0 = 0; k0 < K; k0 += 32) {
    __syncthreads();
    GLOAD16(gA0 + k0, lA0);
    GLOAD16(gA1 + k0, lA1);
    GLOAD16(gB0 + k0, lB0);
    GLOAD16(gB1 + k0, lB1);
    __syncthreads();
    bf16x8 af[4], bf[4];
#pragma unroll
    for (int i = 0; i < 4; i++) {
      af[i] = *(const bf16x8*)(As + aoff[i]);
      bf[i] = *(const bf16x8*)(Bs + boff[i]);
    }
#pragma unroll
    for (int i = 0; i < 4; i++)
#pragma unroll
      for (int j = 0; j < 4; j++)
        acc[i][j] = __builtin_amdgcn_mfma_f32_16x16x32_bf16(af[i], bf[j], acc[i][j], 0, 0, 0);
  }

  // epilogue: restage through LDS in two 64-row halves, full-line fp32 stores
#pragma unroll
  for (int half = 0; half < 2; half++) {
    __syncthreads();
    if (wm == half) {
#pragma unroll
      for (int i = 0; i < 4; i++)
#pragma unroll
        for (int r = 0; r < 4; r++) {
          int rl = i * 16 + qd * 4 + r;
          float bv = bias[m0 + half * 64 + rl];
#pragma unroll
          for (int j = 0; j < 4; j++)
            Cf[rl * 133 + wn * 64 + j * 16 + l15] = acc[i][j][r] + bv;
        }
    }
    __syncthreads();
#pragma unroll
    for (int z = 0; z < 2; z++) {
      int rl = z * 32 + (tid >> 3);
      int seg = tid & 7;
      float* dp = C + (long)(m0 + half * 64 + rl) * ldc + n0;
      const float* src = Cf + rl * 133;
#pragma unroll
      for (int p = 0; p < 4; p++)
        *(float4*)(dp + p * 32 + seg * 4) = *(const float4*)(src + p * 32 + seg * 4);
    }
  }
}

// ------------------------------------------------- launch
extern "C" void kernel_launch(void* const* d_in, const int* in_sizes, int n_in,
                              void* d_out, int out_size, void* d_ws, size_t ws_size,
                              hipStream_t stream) {
  const float* x    = (const float*)d_in[0];
  const float* lnw  = (const float*)d_in[1];
  const float* lnb  = (const float*)d_in[2];
  const float* wqkv = (const float*)d_in[3];
  const float* wout = (const float*)d_in[4];
  const float* bout = (const float*)d_in[5];
  float* out = (float*)d_out;
  char* ws = (char*)d_ws;

  u16*  h     = (u16*)(ws + 0L);              // 32 MB (b,n,d) bf16
  u16*  qexp  = (u16*)(ws + 33554432L);       // 32 MB (b,n,512) bf16
  u16*  expkT = (u16*)(ws + 67108864L);       // 32 MB (b,512,n) bf16
  u16*  vT    = (u16*)(ws + 100663296L);      // 32 MB (b,512,n) bf16
  u16*  wqkvT = (u16*)(ws + 134217728L);      // 1.5 MB
  u16*  Mt    = (u16*)(ws + 134217728L);      // 2 MB, reuses wqkvT region (after gemm1)
  float* S    = (float*)(ws + 136314880L);    // 8 KB
  float* ctx  = (float*)(ws + 0L);            // 512 KB, aliases h (dead after gemm1)
  float* Z    = (float*)d_out;                // 1 MB, dead before gemm_tn_f writes out

  hipMemsetAsync(S, 0, 4 * 512 * 4, stream);
  hipMemsetAsync(Z, 0, (long)B_ * NH * 8192 * 4, stream);

  transpose_f2b<<<dim3(24, 8), 256, 0, stream>>>(wqkv, wqkvT, 512, 1536);

  ln_kernel<<<dim3(256, 4), 256, 0, stream>>>(x, lnw, lnb, h);

  gemm1<<<dim3(12, 256), 256, 0, stream>>>(h, wqkvT, qexp, expkT, vT, S, Z);

  zrecip<<<dim3(1024), 256, 0, stream>>>(Z);

  hipMemsetAsync(ctx, 0, 4 * 8 * 64 * 64 * 4, stream);

  ctx_kernel<<<dim3(16, 8, 4), 256, 0, stream>>>(expkT, vT, Z, ctx);

  mprime<<<dim3(8, 8, 4), 256, 0, stream>>>(ctx, wout, S, Mt);

  gemm_tn_f<<<dim3(4, 64, 4), 256, 0, stream>>>(Mt, qexp, out, bout, 512, 8192,
                                                262144L, (long)8192 * 512, (long)512 * 8192);
}